// Round 8
// baseline (300.325 us; speedup 1.0000x reference)
//
#include <hip/hip_runtime.h>
#include <math.h>

#define IMG_W 3840
#define IMG_H 2160
#define OUTW  120       // output cols per wave (32 strips: 32*120 = 3840 exact)
#define R     20        // output rows per strip (2160 = 108 * 20)
#define ITERS (R + 4)   // gray rows per strip
#define P     3         // prefetch depth (rows in flight)
#define MROWS (R + 2)   // 22 mag rows per wave strip (flat, no ring wrap)
#define CAP   224       // per-wave defer-list capacity (expect ~0.3 used)

// idx -> dx [1,1,0,-1,-1,-1,0,1], dy [0,1,1,1,0,-1,-1,-1], packed as (d+1) 2-bit fields
#define DXPACK 0x901A
#define DYPACK 0x1A9
// Sector boundary slopes in scaled-degree space (RAD2DEG = 180/3.14159)
#define T1_SLOPE 0.41421317376456f
#define T2_SLOPE 2.41420676743300f
#define SECT_EPS  3.0e-5f    // valid: candidates have sA >= mag >= 0.2, approx err ~1e-6 abs
#define QE        0.04f      // 0.2^2 threshold on squared magnitude
#define QBAND_EPS 1.0e-4f
#define TIE_EPS   1.0e-4f

// ---------- exact reference numerics (cold path only) ----------
__device__ __forceinline__ int slow_sector(float sx, float sy) {
#pragma clang fp contract(off)
    const float RADF = (float)(180.0 / 3.14159);
    float t = atan2f(sy, sx);
    float wvv = ((t * RADF) + 180.0f) / 45.0f;  // exact f32 chain as reference
    float ori = rintf(wvv);                     // round-half-even == np.round
    float fr = fabsf(wvv - ori);
    if (fr > 0.4995f) {
        double td = atan2((double)sy, (double)sx);
        float t2 = (float)td;
        wvv = ((t2 * RADF) + 180.0f) / 45.0f;
        ori = rintf(wvv);
    }
    return ((int)ori) & 7;
}

__device__ __forceinline__ float gray_at(const float* img, int xx, int yy) {
#pragma clang fp contract(off)
    if ((unsigned)xx >= (unsigned)IMG_W || (unsigned)yy >= (unsigned)IMG_H) return 0.0f;
    size_t o = (size_t)yy * IMG_W + xx;
    float c0 = img[o];
    float c1 = img[o + (size_t)IMG_W * IMG_H];
    float c2 = img[o + 2 * (size_t)IMG_W * IMG_H];
    return ((c0 + c1) + c2) / 3.0f;             // exact reference gray
}

__device__ void sobel_at(const float* img, int xx, int yy, float& sxo, float& syo) {
#pragma clang fp contract(off)
    float a00 = gray_at(img, xx - 1, yy - 1), a01 = gray_at(img, xx, yy - 1), a02 = gray_at(img, xx + 1, yy - 1);
    float a10 = gray_at(img, xx - 1, yy),                                     a12 = gray_at(img, xx + 1, yy);
    float a20 = gray_at(img, xx - 1, yy + 1), a21 = gray_at(img, xx, yy + 1), a22 = gray_at(img, xx + 1, yy + 1);
    float s = a00;
    s = s - a02;
    s = s + 2.0f * a10;
    s = s - 2.0f * a12;
    s = s + a20;
    s = s - a22;
    sxo = s;
    float t = a00;
    t = t + 2.0f * a01;
    t = t + a02;
    t = t - a20;
    t = t - 2.0f * a21;
    t = t - a22;
    syo = t;
}

__device__ float mag_at(const float* img, int xx, int yy) {
#pragma clang fp contract(off)
    if ((unsigned)xx >= (unsigned)IMG_W || (unsigned)yy >= (unsigned)IMG_H) return 0.0f;
    float sx, sy;
    sobel_at(img, xx, yy, sx, sy);
    return sqrtf(sx * sx + sy * sy);
}

// ---------- main kernel: prefetch-3, div/sqrt-free fast path, in-wave fixup ----------
__global__ __launch_bounds__(256, 3) void canny_main(const float* __restrict__ img,
                                                     float* __restrict__ out) {
    __shared__ float strip[4][MROWS][128];      // squared mags, 44 KB
    __shared__ unsigned fixl[4][CAP];           // deferred pixels, 3.5 KB
    __shared__ unsigned fixn[4];

    const int lane = threadIdx.x;               // 0..63
    const int wv   = threadIdx.y;               // 0..3
    float* sbase = &strip[wv][0][0];
    unsigned* flist = fixl[wv];
    if (lane == 0) fixn[wv] = 0u;               // wave-private; same-wave DS in-order

    const int X0 = (blockIdx.x * 4 + wv) * OUTW;
    const int Y0 = blockIdx.y * R;
    const int r0 = 2 * lane;                    // rel cols r0, r0+1 (image X0-2+r0)
    const int x0i = X0 - 2 + r0;
    const int x1i = x0i + 1;
    const bool xk0 = (unsigned)x0i < (unsigned)IMG_W;
    const bool xk1 = (unsigned)x1i < (unsigned)IMG_W;
    const bool outok = (lane >= 1) && (lane <= 60);   // out cols X0..X0+119
    const int rb = outok ? r0 : 2;              // safe LDS read index for masked lanes
    const int xc = min(max(x0i, 0), IMG_W - 2); // even -> aligned float2

    const float* p0 = img + xc;
    const float* p1 = p0 + (size_t)IMG_W * IMG_H;
    const float* p2 = p1 + (size_t)IMG_W * IMG_H;

    // prefetch pipeline: raw channel rows k..k+P-1 in registers
    float2 rA[P], rB[P], rC[P];
#pragma unroll
    for (int j = 0; j < P; ++j) {
        int yc = min(max(Y0 - 2 + j, 0), IMG_H - 1);
        size_t o = (size_t)yc * IMG_W;
        rA[j] = *(const float2*)(p0 + o);
        rB[j] = *(const float2*)(p1 + o);
        rC[j] = *(const float2*)(p2 + o);
    }

    const float INV3 = 1.0f / 3.0f;
    float GL[3], G0[3], G1[3], GR[3];           // rolling gray rows (4 cols/lane)
    float mq0 = 0.f, mq1 = 0.f;                 // lag-1 center squared mags
    int off0 = 0, off1 = 0;                     // lag-1 flat NMS offsets (dy*128+dx)
    bool bnd0 = false, bnd1 = false;            // lag-1 produce-time defer bands

#pragma unroll
    for (int k = 0; k < ITERS; ++k) {
        const int y = Y0 - 2 + k;
        const bool yok = (unsigned)y < (unsigned)IMG_H;
        const int sl = k % P;                   // static after unroll
        float2 A = rA[sl], B = rB[sl], C = rC[sl];
        if (k + P < ITERS) {                    // compile-time guard
            int yc2 = min(max(y + P, 0), IMG_H - 1);
            size_t o2 = (size_t)yc2 * IMG_W;
            rA[sl] = *(const float2*)(p0 + o2);
            rB[sl] = *(const float2*)(p1 + o2);
            rC[sl] = *(const float2*)(p2 + o2);
        }
        // approx gray (mul by 1/3; exactness recovered via defer bands)
        float g0 = (yok && xk0) ? ((A.x + B.x) + C.x) * INV3 : 0.0f;
        float g1 = (yok && xk1) ? ((A.y + B.y) + C.y) * INV3 : 0.0f;
        const int s = k % 3;
        G0[s] = g0; G1[s] = g1;
        GL[s] = __shfl_up(g1, 1);               // col r0-1
        GR[s] = __shfl_down(g0, 1);             // col r0+2

        if (k >= 2) {
            const int i0 = (k - 2) % 3, i1 = (k - 1) % 3, i2 = k % 3;
            const int m = y - 1;                // mag row
            const bool mok = (unsigned)m < (unsigned)IMG_H;

            // px0 (col r0): taps (GL,G0,G1)
            float sx0 = GL[i0] - G1[i0] + 2.0f * (GL[i1] - G1[i1]) + GL[i2] - G1[i2];
            float sy0 = GL[i0] + 2.0f * G0[i0] + G1[i0] - GL[i2] - 2.0f * G0[i2] - G1[i2];
            float q0v = sx0 * sx0 + sy0 * sy0;  // squared magnitude
            // px1 (col r0+1): taps (G0,G1,GR)
            float sx1 = G0[i0] - GR[i0] + 2.0f * (G0[i1] - GR[i1]) + G0[i2] - GR[i2];
            float sy1 = G0[i0] + 2.0f * G1[i0] + GR[i0] - G0[i2] - 2.0f * G1[i2] - GR[i2];
            float q1v = sx1 * sx1 + sy1 * sy1;

            const bool v0 = mok && xk0, v1 = mok && xk1;
            float Q0 = v0 ? q0v : 0.0f;         // grad_mag zero-padded outside HxW
            float Q1 = v1 ? q1v : 0.0f;

            // sector from slope signs (no atan2)
            float ax0 = fabsf(sx0), ay0 = fabsf(sy0);
            float d10 = fmaf(-T1_SLOPE, ax0, ay0);
            float d20 = fmaf(-T2_SLOPE, ax0, ay0);
            float sA0 = ax0 + ay0;
            int ndx0 = (d20 > 0.0f) ? 0 : ((sx0 > 0.0f) ? -1 : 1);
            int ndy0 = (d10 < 0.0f) ? 0 : ((sy0 > 0.0f) ? -1 : 1);
            bool nb0 = (fabsf(d10) < SECT_EPS * sA0) || (fabsf(d20) < SECT_EPS * sA0)
                     || (fabsf(q0v - QE) <= QBAND_EPS * (q0v + QE));

            float ax1 = fabsf(sx1), ay1 = fabsf(sy1);
            float d11 = fmaf(-T1_SLOPE, ax1, ay1);
            float d21 = fmaf(-T2_SLOPE, ax1, ay1);
            float sA1 = ax1 + ay1;
            int ndx1 = (d21 > 0.0f) ? 0 : ((sx1 > 0.0f) ? -1 : 1);
            int ndy1 = (d11 < 0.0f) ? 0 : ((sy1 > 0.0f) ? -1 : 1);
            bool nb1 = (fabsf(d11) < SECT_EPS * sA1) || (fabsf(d21) < SECT_EPS * sA1)
                     || (fabsf(q1v - QE) <= QBAND_EPS * (q1v + QE));

            // strip row (k-2) holds mag row Y0-1+(k-2); rows are contiguous (flat)
            *(float2*)(sbase + (k - 2) * 128 + r0) = make_float2(Q0, Q1);

            // ---- NMS for row n = Y0+k-4 (rows n-1,n,n+1 = slots k-4,k-3,k-2) ----
            if (k >= 4) {
                float* cp0 = sbase + (k - 3) * 128 + rb;
                float* cp1 = cp0 + 1;
                float mp0 = cp0[off0], mn0 = cp0[-off0];
                float mp1 = cp1[off1], mn1 = cp1[-off1];
                // fast binary decision on squared mags (monotone in true mags)
                float r0v = (mq0 > mp0 && mq0 > mn0 && mq0 >= QE) ? 1.0f : 0.0f;
                float r1v = (mq1 > mp1 && mq1 > mn1 && mq1 >= QE) ? 1.0f : 0.0f;
                if (outok)
                    *(float2*)(out + (size_t)(Y0 + k - 4) * IMG_W + x0i) = make_float2(r0v, r1v);
                // defer knife-edge pixels (bands) to exact recompute
                bool cand0 = mq0 >= QE * (1.0f - 3.0f * QBAND_EPS);
                bool cand1 = mq1 >= QE * (1.0f - 3.0f * QBAND_EPS);
                bool tie0 = (fabsf(mq0 - mp0) <= TIE_EPS * (mq0 + mp0)) ||
                            (fabsf(mq0 - mn0) <= TIE_EPS * (mq0 + mn0));
                bool tie1 = (fabsf(mq1 - mp1) <= TIE_EPS * (mq1 + mp1)) ||
                            (fabsf(mq1 - mn1) <= TIE_EPS * (mq1 + mn1));
                bool f0 = outok && cand0 && (bnd0 || tie0);
                bool f1 = outok && cand1 && (bnd1 || tie1);
                if (f0 || f1) {                 // rare (~0.3 per wave for whole image)
                    int n = Y0 + k - 4;
                    if (f0) {
                        unsigned id = atomicAdd(&fixn[wv], 1u);
                        if (id < CAP) flist[id] = ((unsigned)n << 12) | (unsigned)x0i;
                    }
                    if (f1) {
                        unsigned id = atomicAdd(&fixn[wv], 1u);
                        if (id < CAP) flist[id] = ((unsigned)n << 12) | (unsigned)x1i;
                    }
                }
            }
            mq0 = Q0; mq1 = Q1;
            off0 = v0 ? (ndy0 * 128 + ndx0) : 0;
            off1 = v1 ? (ndy1 * 128 + ndx1) : 0;
            bnd0 = nb0; bnd1 = nb1;
        }
    }

    // ---- in-wave fixup: exact reference numerics for deferred pixels ----
    __threadfence();                            // drain fast-path stores (wave-wide vmcnt)
    unsigned n = fixn[wv];
    if (n > CAP) n = CAP;
    for (unsigned i = lane; i < n; i += 64) {
        unsigned pk = flist[i];
        int xx = (int)(pk & 4095u), yy = (int)(pk >> 12);
        float sx, sy;
        sobel_at(img, xx, yy, sx, sy);          // exact gray (/3.0f) + exact taps
        int idx = slow_sector(sx, sy);          // exact atan2 (+double rescue)
        int dxo = ((DXPACK >> (2 * idx)) & 3) - 1;
        int dyo = ((DYPACK >> (2 * idx)) & 3) - 1;
        float mc = mag_at(img, xx, yy);
        float mp = mag_at(img, xx + dxo, yy + dyo);
        float mn = mag_at(img, xx - dxo, yy - dyo);
        out[(size_t)yy * IMG_W + xx] =
            (fminf(mc - mp, mc - mn) > 0.0f && mc >= 0.2f) ? 1.0f : 0.0f;
    }
}

extern "C" void kernel_launch(void* const* d_in, const int* in_sizes, int n_in,
                              void* d_out, int out_size, void* d_ws, size_t ws_size,
                              hipStream_t stream) {
    const float* img = (const float*)d_in[0];
    float* out = (float*)d_out;
    canny_main<<<dim3(8, IMG_H / R), dim3(64, 4), 0, stream>>>(img, out);
}